// Round 1
// baseline (9387.817 us; speedup 1.0000x reference)
//
#include <hip/hip_runtime.h>
#include <float.h>

// FPS: N=524288 pts, M=2048 selected (idx[0]=0), out = pos[idxs] (2048x3 f32).
// 64 cooperative blocks x 512 threads. Per iteration: distance update ->
// wave butterfly -> LDS (parity dbuf) -> symmetric cross-wave reduce ->
// BLOCK-OWNER THREAD publishes a 4-word slot {tag|val, tag|x, tag|y, tag|z}
// (coords come from its registers -- no pos[] gather on the critical path) ->
// all waves poll packed 32B slots (4 u64 loads/lane, 32 lines total) ->
// value butterfly + ballot + 3x32-bit shuffle broadcast of coords.
// One __syncthreads per iteration, no post-exchange block sync.

#define NPTS     524288
#define MOUT     2048
#define NBLK     64
#define NTHR     512
#define NWAVE    (NTHR / 64)            // 8
#define GTHREADS (NBLK * NTHR)          // 32768
#define PPT      (NPTS / GTHREADS)      // 16
#define SLOTW    4                      // u64 words per slot: V, XW, YW, ZW
#define MASK51   ((1ull << 51) - 1)

// V word: [tag:13][fbits:32][idx_inv:19]
// fbits = IEEE bits of min_d (>=0 so bit order == value order)
// idx_inv = (NPTS-1)-idx: equal values -> smaller idx wins the max
// => first-occurrence tie-break == jnp.argmax (absmax 0.0 in prior rounds).
// Coord words: [tag:13][0:19][float bits:32]. Every word self-tagged, so ALL
// publisher stores are relaxed (no vmcnt fence on the publish path); pollers
// verify coord tags with a rare wave-uniform retry loop (covers store skew).
// Block bests are globally distinct (point ownership partitioned), so the
// winning lane after a reduce is identified by word equality.
// Poison 0xAA.. decodes tag 0x1555, never a real tag (1..2047); monotone tags
// + parity double-buffer + barrier coupling (a block can't publish iter i+2
// until every block passed iter i's poll) keep stale words harmless.

__global__ void __launch_bounds__(NTHR, 1) fps_kernel(
    const float* __restrict__ pos, float* __restrict__ out,
    unsigned long long* __restrict__ slots)
{
    const unsigned tid  = threadIdx.x;
    const unsigned lane = tid & 63u;
    const unsigned wav  = tid >> 6;
    const unsigned blk  = blockIdx.x;
    const unsigned g    = blk * NTHR + tid;

    float X[PPT], Y[PPT], Z[PPT], D[PPT];
#pragma unroll
    for (int p = 0; p < PPT; ++p) {
        const unsigned idx = g + (unsigned)p * GTHREADS;
        X[p] = pos[3u * idx + 0];
        Y[p] = pos[3u * idx + 1];
        Z[p] = pos[3u * idx + 2];
        D[p] = FLT_MAX;
    }

    float px = pos[0], py = pos[1], pz = pos[2];
    if (g == 0) { out[0] = px; out[1] = py; out[2] = pz; }

    // Parity double-buffered cross-wave scratch: a fast wave at iter i+1
    // writes buffer (i+1)&1 while a slow wave may still read buffer i&1.
    __shared__ unsigned long long sred[2][NWAVE];

    for (int i = 1; i < MOUT; ++i) {
        // ---- distance update + per-thread argmax (exact fp32: no FMA,
        // ---- sum order (dx^2+dy^2)+dz^2; bit-exact vs JAX reference) ----
        float bv = -1.0f;
        unsigned bi = 0;
#pragma unroll
        for (int p = 0; p < PPT; ++p) {
            float dx = __fsub_rn(X[p], px);
            float dy = __fsub_rn(Y[p], py);
            float dz = __fsub_rn(Z[p], pz);
            float d  = __fadd_rn(__fadd_rn(__fmul_rn(dx, dx), __fmul_rn(dy, dy)),
                                 __fmul_rn(dz, dz));
            float m  = fminf(D[p], d);
            D[p] = m;
            if (m > bv) { bv = m; bi = g + (unsigned)p * GTHREADS; }
        }

        // ---- recover own-best coords with STATIC indices (no scratch);
        // ---- pure VALU chain, overlaps the DS butterfly below ----
        float bx = X[0], by = Y[0], bz = Z[0];
#pragma unroll
        for (int p = 1; p < PPT; ++p) {
            const bool w = (bi == g + (unsigned)p * GTHREADS);
            bx = w ? X[p] : bx;
            by = w ? Y[p] : by;
            bz = w ? Z[p] : bz;
        }

        const unsigned long long mine =
            ((unsigned long long)__float_as_uint(bv) << 19) |
            (unsigned long long)((NPTS - 1u) - bi);

        // ---- wave butterfly: all lanes get wave best ----
        unsigned long long best = mine;
#pragma unroll
        for (int off = 32; off > 0; off >>= 1) {
            unsigned long long o = __shfl_xor(best, off, 64);
            if (o > best) best = o;
        }

        // ---- cross-wave reduce, symmetric: every thread computes block best ----
        unsigned long long* sb = sred[i & 1];
        if (lane == 0) sb[wav] = best;
        __syncthreads();
        unsigned long long b2 = sb[lane & (NWAVE - 1u)];
#pragma unroll
        for (int off = NWAVE / 2; off > 0; off >>= 1) {
            unsigned long long o = __shfl_xor(b2, off, 64);
            if (o > b2) b2 = o;
        }

        const unsigned long long tag = (unsigned long long)i;
        const unsigned long long tb  = tag << 51;
        unsigned long long* buf = slots + (unsigned)(i & 1) * (NBLK * SLOTW);

        // ---- block owner (unique: packed words are globally distinct)
        // ---- publishes value + its registers' coords; all stores relaxed ----
        if (mine == b2) {
            unsigned long long* s0 = buf + blk * SLOTW;
            __hip_atomic_store(s0 + 1, tb | (unsigned long long)__float_as_uint(bx),
                               __ATOMIC_RELAXED, __HIP_MEMORY_SCOPE_AGENT);
            __hip_atomic_store(s0 + 2, tb | (unsigned long long)__float_as_uint(by),
                               __ATOMIC_RELAXED, __HIP_MEMORY_SCOPE_AGENT);
            __hip_atomic_store(s0 + 3, tb | (unsigned long long)__float_as_uint(bz),
                               __ATOMIC_RELAXED, __HIP_MEMORY_SCOPE_AGENT);
            __hip_atomic_store(s0 + 0, tb | b2,
                               __ATOMIC_RELAXED, __HIP_MEMORY_SCOPE_AGENT);
        }

        // ---- every wave polls all 64 packed slots (1 slot = 4 u64 per lane);
        // ---- coords arrive with the tag -> zero exposed gather after detect ----
        unsigned long long* sl = buf + lane * SLOTW;
        unsigned long long v, xw, yw, zw;
        do {
            v  = __hip_atomic_load(sl + 0, __ATOMIC_RELAXED, __HIP_MEMORY_SCOPE_AGENT);
            xw = __hip_atomic_load(sl + 1, __ATOMIC_RELAXED, __HIP_MEMORY_SCOPE_AGENT);
            yw = __hip_atomic_load(sl + 2, __ATOMIC_RELAXED, __HIP_MEMORY_SCOPE_AGENT);
            zw = __hip_atomic_load(sl + 3, __ATOMIC_RELAXED, __HIP_MEMORY_SCOPE_AGENT);
            if ((v >> 51) == tag) break;
            __builtin_amdgcn_s_sleep(1);
        } while (true);

        // rare retry: coord words were issued before V but relaxed stores may
        // skew; wave-uniform loop, usually zero extra rounds
        while (__ballot(((xw >> 51) != tag) | ((yw >> 51) != tag) |
                        ((zw >> 51) != tag)) != 0ull) {
            xw = __hip_atomic_load(sl + 1, __ATOMIC_RELAXED, __HIP_MEMORY_SCOPE_AGENT);
            yw = __hip_atomic_load(sl + 2, __ATOMIC_RELAXED, __HIP_MEMORY_SCOPE_AGENT);
            zw = __hip_atomic_load(sl + 3, __ATOMIC_RELAXED, __HIP_MEMORY_SCOPE_AGENT);
        }

        // ---- winner reduce over the 64 block bests (tag bits are uniform) ----
        unsigned long long win = v;
#pragma unroll
        for (int off = 32; off > 0; off >>= 1) {
            unsigned long long o = __shfl_xor(win, off, 64);
            if (o > win) win = o;
        }
        unsigned long long bal = __ballot(win == v);   // exactly one lane matches
        int src = __ffsll(bal) - 1;
        px = __shfl(__uint_as_float((unsigned)xw), src, 64);
        py = __shfl(__uint_as_float((unsigned)yw), src, 64);
        pz = __shfl(__uint_as_float((unsigned)zw), src, 64);

        if (blk == 0 && tid == 0) {
            out[3 * i + 0] = px; out[3 * i + 1] = py; out[3 * i + 2] = pz;
        }
        // no trailing __syncthreads: next iteration's pre-publish sync +
        // parity-dbuf LDS + tag monotonicity make the tail race-free.
    }
}

extern "C" void kernel_launch(void* const* d_in, const int* in_sizes, int n_in,
                              void* d_out, int out_size, void* d_ws, size_t ws_size,
                              hipStream_t stream) {
    const float* pos = (const float*)d_in[0];
    float* out = (float*)d_out;
    unsigned long long* slots = (unsigned long long*)d_ws;  // 2 x 64 x 32B = 4 KB
    // No memset: 0xAA poison decodes to tag 0x1555, never a real tag (1..2047);
    // monotone tags + 2-buffer rotation make stale words harmless.

    void* args[] = { (void*)&pos, (void*)&out, (void*)&slots };
    hipLaunchCooperativeKernel((void*)fps_kernel, dim3(NBLK), dim3(NTHR),
                               args, 0, stream);
}

// Round 2
// 5164.612 us; speedup vs baseline: 1.8177x; 1.8177x over previous
//
#include <hip/hip_runtime.h>
#include <float.h>

// FPS: N=524288 pts, M=2048 selected (idx[0]=0), out = pos[idxs] (2048x3 f32).
// 64 cooperative blocks x 512 threads. Per iteration: distance update ->
// wave butterfly -> LDS (parity dbuf) -> WAVE 0 ONLY: cross-wave reduce,
// publish tagged padded slot, poll the 64 fabric slots (1 slot/lane),
// prefetched-coord gather + butterfly + shuffle -> LDS coord broadcast
// {tag|x, tag|y, tag|z}; waves 1-7 spin on LDS (bank-broadcast reads, zero
// fabric traffic). One __syncthreads per iteration.
// R1 lesson: agent-scope poll loads bypass per-XCD L2 -- every poll attempt
// is a fabric read, and 512 polling waves were the contention driver. This
// version has 64 polling waves (8x less read pressure on the slot lines).

#define NPTS     524288
#define MOUT     2048
#define NBLK     64
#define NTHR     512
#define NWAVE    (NTHR / 64)            // 8
#define GTHREADS (NBLK * NTHR)          // 32768
#define PPT      (NPTS / GTHREADS)      // 16
#define SLOT_STRIDE 8                   // u64 per slot -> 64 B line per publisher
#define MASK51   ((1ull << 51) - 1)

// slot word: [tag:13][fbits:32][idx_inv:19]
// fbits = IEEE bits of min_d (>=0 so bit order == value order)
// idx_inv = (NPTS-1)-idx: equal values -> smaller idx wins the max
// => first-occurrence tie-break == jnp.argmax (absmax 0.0 in R0).
// Block bests are globally distinct (point ownership partitioned), so the
// winning lane after a reduce is identified by word equality.
// LDS broadcast words: [tag:13][0:19][float bits:32], each self-tagged ->
// relaxed ds stores/loads suffice; parity dbuf + monotone tags kill staleness.
// Poison 0xAA.. decodes to tag 0x1555 (never a real tag 1..2047).

__global__ void __launch_bounds__(NTHR, 1) fps_kernel(
    const float* __restrict__ pos, float* __restrict__ out,
    unsigned long long* __restrict__ slots)
{
    const unsigned tid  = threadIdx.x;
    const unsigned lane = tid & 63u;
    const unsigned wav  = tid >> 6;
    const unsigned blk  = blockIdx.x;
    const unsigned g    = blk * NTHR + tid;

    float X[PPT], Y[PPT], Z[PPT], D[PPT];
#pragma unroll
    for (int p = 0; p < PPT; ++p) {
        const unsigned idx = g + (unsigned)p * GTHREADS;
        X[p] = pos[3u * idx + 0];
        Y[p] = pos[3u * idx + 1];
        Z[p] = pos[3u * idx + 2];
        D[p] = FLT_MAX;
    }

    float px = pos[0], py = pos[1], pz = pos[2];
    if (g == 0) { out[0] = px; out[1] = py; out[2] = pz; }

    // Parity double-buffered cross-wave scratch (wave bests -> wave 0).
    __shared__ unsigned long long sred[2][NWAVE];
    // Parity double-buffered coord broadcast (wave 0 -> waves 1-7).
    __shared__ unsigned long long sbc[2][4];   // words 0..2 used
    if (tid < 4) { sbc[0][tid] = 0ull; sbc[1][tid] = 0ull; }  // tag 0 = invalid

    for (int i = 1; i < MOUT; ++i) {
        // ---- distance update + per-thread argmax (exact fp32: no FMA,
        // ---- sum order (dx^2+dy^2)+dz^2; absmax==0 verified) ----
        float bv = -1.0f;
        unsigned bi = 0;
#pragma unroll
        for (int p = 0; p < PPT; ++p) {
            float dx = __fsub_rn(X[p], px);
            float dy = __fsub_rn(Y[p], py);
            float dz = __fsub_rn(Z[p], pz);
            float d  = __fadd_rn(__fadd_rn(__fmul_rn(dx, dx), __fmul_rn(dy, dy)),
                                 __fmul_rn(dz, dz));
            float m  = fminf(D[p], d);
            D[p] = m;
            if (m > bv) { bv = m; bi = g + (unsigned)p * GTHREADS; }
        }
        unsigned long long best =
            ((unsigned long long)__float_as_uint(bv) << 19) |
            (unsigned long long)((NPTS - 1u) - bi);

        // ---- wave butterfly: all lanes get wave best ----
#pragma unroll
        for (int off = 32; off > 0; off >>= 1) {
            unsigned long long o = __shfl_xor(best, off, 64);
            if (o > best) best = o;
        }

        unsigned long long* sb = sred[i & 1];
        if (lane == 0) sb[wav] = best;
        __syncthreads();

        const unsigned long long tag = (unsigned long long)i;
        const unsigned long long tb  = tag << 51;

        if (wav == 0) {
            // ---- cross-wave reduce (wave 0 only) ----
            unsigned long long b2 = sb[lane & (NWAVE - 1u)];
#pragma unroll
            for (int off = NWAVE / 2; off > 0; off >>= 1) {
                unsigned long long o = __shfl_xor(b2, off, 64);
                if (o > b2) b2 = o;
            }

            unsigned long long* buf =
                slots + (unsigned)(i & 1) * (NBLK * SLOT_STRIDE);
            if (lane == 0) {
                __hip_atomic_store(&buf[blk * SLOT_STRIDE], tb | b2,
                                   __ATOMIC_RELAXED, __HIP_MEMORY_SCOPE_AGENT);
            }

            // ---- wave 0 polls all 64 slots (1 padded slot per lane) ----
            unsigned long long s;
            do {
                s = __hip_atomic_load(&buf[lane * SLOT_STRIDE],
                                      __ATOMIC_RELAXED, __HIP_MEMORY_SCOPE_AGENT);
                if ((s >> 51) == tag) break;
                __builtin_amdgcn_s_sleep(1);
            } while (true);
            unsigned long long c = s & MASK51;

            // prefetch this lane's candidate coords; loads fly during butterfly
            unsigned cidx = (NPTS - 1u) - (unsigned)(c & 0x7FFFFull);
            float cx = pos[3u * cidx + 0];
            float cy = pos[3u * cidx + 1];
            float cz = pos[3u * cidx + 2];

            unsigned long long win = c;
#pragma unroll
            for (int off = 32; off > 0; off >>= 1) {
                unsigned long long o = __shfl_xor(win, off, 64);
                if (o > win) win = o;
            }
            unsigned long long bal = __ballot(win == c); // exactly one lane
            int src = __ffsll(bal) - 1;
            px = __shfl(cx, src, 64);
            py = __shfl(cy, src, 64);
            pz = __shfl(cz, src, 64);

            // ---- LDS coord broadcast to waves 1-7 (self-tagged words) ----
            if (lane < 3) {
                float cv = (lane == 0) ? px : (lane == 1) ? py : pz;
                __hip_atomic_store(&sbc[i & 1][lane],
                                   tb | (unsigned long long)__float_as_uint(cv),
                                   __ATOMIC_RELAXED, __HIP_MEMORY_SCOPE_WORKGROUP);
            }

            if (blk == 0 && lane == 0) {
                out[3 * i + 0] = px; out[3 * i + 1] = py; out[3 * i + 2] = pz;
            }
        } else {
            // ---- waves 1-7: spin on LDS broadcast (no fabric traffic) ----
            unsigned long long xw, yw, zw;
            do {
                xw = __hip_atomic_load(&sbc[i & 1][0],
                                       __ATOMIC_RELAXED, __HIP_MEMORY_SCOPE_WORKGROUP);
                yw = __hip_atomic_load(&sbc[i & 1][1],
                                       __ATOMIC_RELAXED, __HIP_MEMORY_SCOPE_WORKGROUP);
                zw = __hip_atomic_load(&sbc[i & 1][2],
                                       __ATOMIC_RELAXED, __HIP_MEMORY_SCOPE_WORKGROUP);
                if (((xw >> 51) == tag) & ((yw >> 51) == tag) &
                    ((zw >> 51) == tag)) break;
                __builtin_amdgcn_s_sleep(1);
            } while (true);
            px = __uint_as_float((unsigned)xw);
            py = __uint_as_float((unsigned)yw);
            pz = __uint_as_float((unsigned)zw);
        }
        // no trailing __syncthreads: next iteration's pre-publish sync +
        // parity dbufs (sred, sbc) + monotone tags make the tail race-free.
    }
}

extern "C" void kernel_launch(void* const* d_in, const int* in_sizes, int n_in,
                              void* d_out, int out_size, void* d_ws, size_t ws_size,
                              hipStream_t stream) {
    const float* pos = (const float*)d_in[0];
    float* out = (float*)d_out;
    unsigned long long* slots = (unsigned long long*)d_ws;  // 2 x 64 x 64B = 8 KB
    // No memset: 0xAA poison decodes to tag 0x1555, never a real tag (1..2047);
    // monotone tags + 2-buffer rotation make stale words harmless.

    void* args[] = { (void*)&pos, (void*)&out, (void*)&slots };
    hipLaunchCooperativeKernel((void*)fps_kernel, dim3(NBLK), dim3(NTHR),
                               args, 0, stream);
}